// Round 4
// baseline (555.822 us; speedup 1.0000x reference)
//
#include <hip/hip_runtime.h>
#include <math.h>

#define NG 1000
#define BKT 32      // nodes per bucket
#define BBITS 5
#define SUBC 4      // sub-cursors per bucket (cuts append-atomic contention)

// ---- per-edge counting: node in-degree + bucket sub-counts ----
__global__ void count_kernel(const int* __restrict__ dst, int* __restrict__ degi,
                             int* __restrict__ bcnt, int E) {
    int i = blockIdx.x * blockDim.x + threadIdx.x;
    if (i >= E) return;
    int d = dst[i];
    atomicAdd(&degi[d], 1);
    atomicAdd(&bcnt[(d >> BBITS) * SUBC + (i & (SUBC - 1))], 1);
}

__global__ void dinv_kernel(const int* __restrict__ degi, float* __restrict__ dinv, int N) {
    int i = blockIdx.x * blockDim.x + threadIdx.x;
    if (i < N) dinv[i] = rsqrtf((float)degi[i] + 1.0f);   // self-loop adds +1
}

// ---- single-block exclusive scan over M ~ 12.5K sub-bucket counts ----
__global__ void __launch_bounds__(1024) scan_kernel(const int* __restrict__ bcnt,
                                                    int* __restrict__ boff,
                                                    int* __restrict__ cur, int M) {
    __shared__ int sm[1024];
    int t = threadIdx.x;
    int chunk = (M + 1023) / 1024;
    int beg = t * chunk, end = beg + chunk;
    if (end > M) end = M;
    int s = 0;
    for (int i = beg; i < end; i++) s += bcnt[i];
    sm[t] = s;
    __syncthreads();
    for (int o = 1; o < 1024; o <<= 1) {
        int u = (t >= o) ? sm[t - o] : 0;
        __syncthreads();
        sm[t] += u;
        __syncthreads();
    }
    int run = sm[t] - s;   // exclusive prefix
    for (int i = beg; i < end; i++) {
        int v = bcnt[i];
        boff[i] = run;
        cur[i] = run;
        run += v;
        if (i == M - 1) boff[M] = run;
    }
}

// ---- scatter edges into bucket-grouped order (packed: local<<27 | src) ----
__global__ void scatter_kernel(const int* __restrict__ src, const int* __restrict__ dst,
                               int* __restrict__ cur, unsigned* __restrict__ ebuf, int E) {
    int i = blockIdx.x * blockDim.x + threadIdx.x;
    if (i >= E) return;
    int s = src[i], d = dst[i];
    int ci = (d >> BBITS) * SUBC + (i & (SUBC - 1));
    int pos = atomicAdd(&cur[ci], 1);
    ebuf[pos] = ((unsigned)(d & (BKT - 1)) << 27) | (unsigned)s;
}

// ---- A1[N,16] = X[N,32] @ W1[16,32]^T ----
__global__ void xform32_16(const float* __restrict__ X, const float* __restrict__ W,
                           float* __restrict__ Y, int N) {
    __shared__ float sW[16 * 32];
    for (int t = threadIdx.x; t < 512; t += blockDim.x) sW[t] = W[t];
    __syncthreads();
    int i = blockIdx.x * blockDim.x + threadIdx.x;
    if (i >= N) return;
    float xv[32];
    const float4* xp = (const float4*)(X + (size_t)i * 32);
#pragma unroll
    for (int q = 0; q < 8; q++) {
        float4 v = xp[q];
        xv[4*q+0] = v.x; xv[4*q+1] = v.y; xv[4*q+2] = v.z; xv[4*q+3] = v.w;
    }
    float4* yp = (float4*)(Y + (size_t)i * 16);
#pragma unroll
    for (int j4 = 0; j4 < 4; j4++) {
        float acc[4];
#pragma unroll
        for (int jj = 0; jj < 4; jj++) {
            int j = j4 * 4 + jj;
            float a = 0.f;
#pragma unroll
            for (int k = 0; k < 32; k++) a += xv[k] * sW[j * 32 + k];
            acc[jj] = a;
        }
        float4 o; o.x = acc[0]; o.y = acc[1]; o.z = acc[2]; o.w = acc[3];
        yp[j4] = o;
    }
}

// ---- layer-1: LDS-accumulate bucket, + self + b1 + relu, then @W2^T -> A2 ----
__global__ void __launch_bounds__(256) agg1_kernel(
    const int* __restrict__ boff, const unsigned* __restrict__ ebuf,
    const float* __restrict__ dinv, const float* __restrict__ A1,
    const float* __restrict__ b1, const float* __restrict__ W2,
    float* __restrict__ A2, int N) {
    __shared__ float acc[BKT][17];   // +1 pad: spreads LDS-atomic banks
    __shared__ float ldd[BKT];
    __shared__ float sW2[256];
    __shared__ float sb1[16];
    int b = blockIdx.x, t = threadIdx.x;
    int base = b * BKT;
    sW2[t] = W2[t];
    if (t < 16) sb1[t] = b1[t];
    if (t < BKT) {
        int n = base + t;
        ldd[t] = (n < N) ? dinv[n] : 0.f;
    }
    for (int k = t; k < BKT * 17; k += 256) ((float*)acc)[k] = 0.f;
    __syncthreads();

    int ebeg = boff[b * SUBC], eend = boff[b * SUBC + SUBC];
    const float4* H4 = (const float4*)A1;
    int q = t & 3;
    for (int e = ebeg + (t >> 2); e < eend; e += 64) {
        unsigned u = ebuf[e];
        int s = (int)(u & 0x7FFFFFFu);
        int local = (int)(u >> 27);
        float nrm = dinv[s] * ldd[local];
        float4 h = H4[(size_t)s * 4 + q];
        atomicAdd(&acc[local][q * 4 + 0], h.x * nrm);
        atomicAdd(&acc[local][q * 4 + 1], h.y * nrm);
        atomicAdd(&acc[local][q * 4 + 2], h.z * nrm);
        atomicAdd(&acc[local][q * 4 + 3], h.w * nrm);
    }
    __syncthreads();

    // epilogue: row = relu(acc + self*dinv^2 + b1), in place
    if (t < BKT * 4) {
        int n = t >> 2, qq = t & 3;
        int node = base + n;
        if (node < N) {
            float dd = ldd[n], s2 = dd * dd;
            float4 sv = H4[(size_t)node * 4 + qq];
            acc[n][qq*4+0] = fmaxf(acc[n][qq*4+0] + sv.x * s2 + sb1[qq*4+0], 0.f);
            acc[n][qq*4+1] = fmaxf(acc[n][qq*4+1] + sv.y * s2 + sb1[qq*4+1], 0.f);
            acc[n][qq*4+2] = fmaxf(acc[n][qq*4+2] + sv.z * s2 + sb1[qq*4+2], 0.f);
            acc[n][qq*4+3] = fmaxf(acc[n][qq*4+3] + sv.w * s2 + sb1[qq*4+3], 0.f);
        }
    }
    __syncthreads();

    // fused transform: A2[node] = row @ W2^T
    if (t < BKT * 4) {
        int n = t >> 2, qq = t & 3;
        int node = base + n;
        if (node < N) {
            float o[4];
#pragma unroll
            for (int jj = 0; jj < 4; jj++) {
                int j = qq * 4 + jj;
                float a = 0.f;
#pragma unroll
                for (int k = 0; k < 16; k++) a += acc[n][k] * sW2[j * 16 + k];
                o[jj] = a;
            }
            float4 ov; ov.x = o[0]; ov.y = o[1]; ov.z = o[2]; ov.w = o[3];
            ((float4*)A2)[(size_t)node * 4 + qq] = ov;
        }
    }
}

// ---- layer-2: LDS-accumulate bucket, + self, then segmented mean-pool flush ----
__global__ void __launch_bounds__(256) agg2_kernel(
    const int* __restrict__ boff, const unsigned* __restrict__ ebuf,
    const float* __restrict__ dinv, const float* __restrict__ A2,
    const int* __restrict__ batch, float* __restrict__ pooled,
    float* __restrict__ cnt, int N) {
    __shared__ float acc[BKT][17];
    __shared__ float ldd[BKT];
    __shared__ int ldsg[BKT];
    int b = blockIdx.x, t = threadIdx.x;
    int base = b * BKT;
    if (t < BKT) {
        int n = base + t;
        ldd[t] = (n < N) ? dinv[n] : 0.f;
    }
    for (int k = t; k < BKT * 17; k += 256) ((float*)acc)[k] = 0.f;
    __syncthreads();

    int ebeg = boff[b * SUBC], eend = boff[b * SUBC + SUBC];
    const float4* H4 = (const float4*)A2;
    int q = t & 3;
    for (int e = ebeg + (t >> 2); e < eend; e += 64) {
        unsigned u = ebuf[e];
        int s = (int)(u & 0x7FFFFFFu);
        int local = (int)(u >> 27);
        float nrm = dinv[s] * ldd[local];
        float4 h = H4[(size_t)s * 4 + q];
        atomicAdd(&acc[local][q * 4 + 0], h.x * nrm);
        atomicAdd(&acc[local][q * 4 + 1], h.y * nrm);
        atomicAdd(&acc[local][q * 4 + 2], h.z * nrm);
        atomicAdd(&acc[local][q * 4 + 3], h.w * nrm);
    }
    __syncthreads();

    if (t < BKT) {
        int n = base + t;
        ldsg[t] = (n < N) ? batch[n] : -1;
    }
    if (t < BKT * 4) {   // finish rows: + self*dinv^2 (b2 deferred to head)
        int n = t >> 2, qq = t & 3;
        int node = base + n;
        if (node < N) {
            float dd = ldd[n], s2 = dd * dd;
            float4 sv = H4[(size_t)node * 4 + qq];
            acc[n][qq*4+0] += sv.x * s2;
            acc[n][qq*4+1] += sv.y * s2;
            acc[n][qq*4+2] += sv.z * s2;
            acc[n][qq*4+3] += sv.w * s2;
        }
    }
    __syncthreads();

    // segmented pool flush (batch sorted): ~1-2 boundaries per bucket
    int nmax = N - base; if (nmax > BKT) nmax = BKT;
    if (t < 16 && nmax > 0) {
        int c = t;
        int g = ldsg[0];
        float a = 0.f, k = 0.f;
        for (int n = 0; n < nmax; n++) {
            int gi = ldsg[n];
            if (gi != g) {
                atomicAdd(&pooled[(size_t)g * 16 + c], a);
                if (c == 0) atomicAdd(&cnt[g], k);
                a = 0.f; k = 0.f; g = gi;
            }
            a += acc[n][c];
            k += 1.f;
        }
        atomicAdd(&pooled[(size_t)g * 16 + c], a);
        if (c == 0) atomicAdd(&cnt[g], k);
    }
}

// ---- head: mean finish (+b2), logits = pooled @ Wl^T + bl, softmax ----
__global__ void head_kernel(const float* __restrict__ pooled, const float* __restrict__ cnt,
                            const float* __restrict__ b2, const float* __restrict__ Wl,
                            const float* __restrict__ bl, float* __restrict__ out) {
    int g = blockIdx.x * blockDim.x + threadIdx.x;
    if (g >= NG) return;
    float c = cnt[g];
    c = c > 1.0f ? c : 1.0f;
    float inv = 1.0f / c;
    float p[16];
#pragma unroll
    for (int j = 0; j < 16; j++) p[j] = pooled[(size_t)g * 16 + j] * inv + b2[j];
    float logits[5], m = -INFINITY;
#pragma unroll
    for (int r = 0; r < 5; r++) {
        float a = bl[r];
#pragma unroll
        for (int j = 0; j < 16; j++) a += p[j] * Wl[r * 16 + j];
        logits[r] = a;
        m = fmaxf(m, a);
    }
    float s = 0.f;
#pragma unroll
    for (int r = 0; r < 5; r++) { logits[r] = expf(logits[r] - m); s += logits[r]; }
    float is = 1.0f / s;
#pragma unroll
    for (int r = 0; r < 5; r++) out[(size_t)g * 5 + r] = logits[r] * is;
}

static inline size_t rnd16b(size_t bytes) { return (bytes + 15) & ~(size_t)15; }

extern "C" void kernel_launch(void* const* d_in, const int* in_sizes, int n_in,
                              void* d_out, int out_size, void* d_ws, size_t ws_size,
                              hipStream_t stream) {
    const float* x     = (const float*)d_in[0];
    const int*   edge  = (const int*)d_in[1];   // [2, E]: first E = src, next E = dst
    const int*   batch = (const int*)d_in[2];
    const float* W1    = (const float*)d_in[3];
    const float* b1    = (const float*)d_in[4];
    const float* W2    = (const float*)d_in[5];
    const float* b2    = (const float*)d_in[6];
    const float* Wl    = (const float*)d_in[7];
    const float* bl    = (const float*)d_in[8];

    const int N = in_sizes[0] / 32;
    const int E = in_sizes[1] / 2;
    const int* src = edge;
    const int* dst = edge + E;

    const int NB = (N + BKT - 1) / BKT;
    const int M  = NB * SUBC;

    // workspace layout (16B-aligned chunks); zeroed region first
    char* ws = (char*)d_ws;
    size_t off = 0;
    int*      degi   = (int*)(ws + off);      off += rnd16b((size_t)N * 4);
    int*      bcnt   = (int*)(ws + off);      off += rnd16b((size_t)M * 4);
    float*    pooled = (float*)(ws + off);    off += rnd16b((size_t)NG * 16 * 4);
    float*    cnt    = (float*)(ws + off);    off += rnd16b((size_t)NG * 4);
    size_t zbytes = off;
    float*    dinv   = (float*)(ws + off);    off += rnd16b((size_t)N * 4);
    int*      boff   = (int*)(ws + off);      off += rnd16b((size_t)(M + 1) * 4);
    int*      cur    = (int*)(ws + off);      off += rnd16b((size_t)M * 4);
    unsigned* ebuf   = (unsigned*)(ws + off); off += rnd16b((size_t)E * 4);
    float*    A1     = (float*)(ws + off);    off += rnd16b((size_t)N * 16 * 4);
    float*    A2     = (float*)(ws + off);    off += rnd16b((size_t)N * 16 * 4);

    hipMemsetAsync(d_ws, 0, zbytes, stream);

    const int BS = 256;
    int gE = (E + BS - 1) / BS;
    int gN = (N + BS - 1) / BS;

    count_kernel<<<gE, BS, 0, stream>>>(dst, degi, bcnt, E);
    dinv_kernel<<<gN, BS, 0, stream>>>(degi, dinv, N);
    scan_kernel<<<1, 1024, 0, stream>>>(bcnt, boff, cur, M);
    scatter_kernel<<<gE, BS, 0, stream>>>(src, dst, cur, ebuf, E);

    xform32_16<<<gN, BS, 0, stream>>>(x, W1, A1, N);
    agg1_kernel<<<NB, 256, 0, stream>>>(boff, ebuf, dinv, A1, b1, W2, A2, N);
    agg2_kernel<<<NB, 256, 0, stream>>>(boff, ebuf, dinv, A2, batch, pooled, cnt, N);
    head_kernel<<<(NG + BS - 1) / BS, BS, 0, stream>>>(pooled, cnt, b2, Wl, bl, (float*)d_out);
}

// Round 5
// 500.103 us; speedup vs baseline: 1.1114x; 1.1114x over previous
//
#include <hip/hip_runtime.h>
#include <hip/hip_fp16.h>
#include <math.h>

#define NG 1000
#define BKT 32      // nodes per bucket
#define BBITS 5
#define SUBC 4      // sub-cursors per bucket

// ---- bucket sub-counts only (1 atomic per edge) ----
__global__ void count_kernel(const int* __restrict__ dst, int* __restrict__ bcnt, int E) {
    int i = blockIdx.x * blockDim.x + threadIdx.x;
    if (i >= E) return;
    atomicAdd(&bcnt[(dst[i] >> BBITS) * SUBC + (i & (SUBC - 1))], 1);
}

// ---- single-block exclusive scan over M sub-bucket counts -> boff, cur ----
__global__ void __launch_bounds__(1024) scan_kernel(const int* __restrict__ bcnt,
                                                    int* __restrict__ boff,
                                                    int* __restrict__ cur, int M) {
    __shared__ int sm[1024];
    int t = threadIdx.x;
    int chunk = (M + 1023) / 1024;
    int beg = t * chunk, end = beg + chunk;
    if (end > M) end = M;
    int s = 0;
    for (int i = beg; i < end; i++) s += bcnt[i];
    sm[t] = s;
    __syncthreads();
    for (int o = 1; o < 1024; o <<= 1) {
        int u = (t >= o) ? sm[t - o] : 0;
        __syncthreads();
        sm[t] += u;
        __syncthreads();
    }
    int run = sm[t] - s;
    for (int i = beg; i < end; i++) {
        int v = bcnt[i];
        boff[i] = run;
        cur[i] = run;
        run += v;
        if (i == M - 1) boff[M] = run;
    }
}

// ---- scatter edges into bucket-grouped order (packed: local<<27 | src) ----
__global__ void scatter_kernel(const int* __restrict__ src, const int* __restrict__ dst,
                               int* __restrict__ cur, unsigned* __restrict__ ebuf, int E) {
    int i = blockIdx.x * blockDim.x + threadIdx.x;
    if (i >= E) return;
    int s = src[i], d = dst[i];
    int ci = (d >> BBITS) * SUBC + (i & (SUBC - 1));
    int pos = atomicAdd(&cur[ci], 1);
    ebuf[pos] = ((unsigned)(d & (BKT - 1)) << 27) | (unsigned)s;
}

// ---- per-bucket degree histogram from ebuf -> degi ----
__global__ void __launch_bounds__(256) hist_kernel(const int* __restrict__ boff,
                                                   const unsigned* __restrict__ ebuf,
                                                   int* __restrict__ degi, int N) {
    __shared__ int hcnt[BKT];
    int b = blockIdx.x, t = threadIdx.x;
    if (t < BKT) hcnt[t] = 0;
    __syncthreads();
    int ebeg = boff[b * SUBC], eend = boff[b * SUBC + SUBC];
    for (int e = ebeg + t; e < eend; e += 256) atomicAdd(&hcnt[ebuf[e] >> 27], 1);
    __syncthreads();
    int n = b * BKT + t;
    if (t < BKT && n < N) degi[n] = hcnt[t];
}

__global__ void dinv_kernel(const int* __restrict__ degi, float* __restrict__ dinv, int N) {
    int i = blockIdx.x * blockDim.x + threadIdx.x;
    if (i < N) dinv[i] = rsqrtf((float)degi[i] + 1.0f);   // self-loop adds +1
}

// ---- A1h[N,16] (fp16) = (X[N,32] @ W1^T) * dinv[i] ----
__global__ void xform1_kernel(const float* __restrict__ X, const float* __restrict__ W,
                              const float* __restrict__ dinv, __half* __restrict__ A1h, int N) {
    __shared__ float sW[16 * 32];
    for (int t = threadIdx.x; t < 512; t += blockDim.x) sW[t] = W[t];
    __syncthreads();
    int i = blockIdx.x * blockDim.x + threadIdx.x;
    if (i >= N) return;
    float xv[32];
    const float4* xp = (const float4*)(X + (size_t)i * 32);
#pragma unroll
    for (int q = 0; q < 8; q++) {
        float4 v = xp[q];
        xv[4*q+0] = v.x; xv[4*q+1] = v.y; xv[4*q+2] = v.z; xv[4*q+3] = v.w;
    }
    float dd = dinv[i];
    union { __half2 h2[8]; uint4 u4[2]; } pk;
#pragma unroll
    for (int j2 = 0; j2 < 8; j2++) {
        float o[2];
#pragma unroll
        for (int jj = 0; jj < 2; jj++) {
            int j = j2 * 2 + jj;
            float a = 0.f;
#pragma unroll
            for (int k = 0; k < 32; k++) a += xv[k] * sW[j * 32 + k];
            o[jj] = a * dd;
        }
        pk.h2[j2] = __floats2half2_rn(o[0], o[1]);
    }
    uint4* yp = (uint4*)(A1h + (size_t)i * 16);
    yp[0] = pk.u4[0];
    yp[1] = pk.u4[1];
}

__device__ __forceinline__ void edge_accum(unsigned u, int q, const uint2* __restrict__ H2,
                                           float (*acc)[17]) {
    int s = (int)(u & 0x7FFFFFFu);
    int loc = (int)(u >> 27);
    uint2 v = H2[(size_t)s * 4 + q];
    __half2 h0 = *(const __half2*)&v.x;
    __half2 h1 = *(const __half2*)&v.y;
    float2 f0 = __half22float2(h0), f1 = __half22float2(h1);
    atomicAdd(&acc[loc][q * 4 + 0], f0.x);
    atomicAdd(&acc[loc][q * 4 + 1], f0.y);
    atomicAdd(&acc[loc][q * 4 + 2], f1.x);
    atomicAdd(&acc[loc][q * 4 + 3], f1.y);
}

// ---- layer-1: bucket accumulate; out = relu(dinv*(sum+self)+b1); A2h = (out@W2^T)*dinv ----
__global__ void __launch_bounds__(256) agg1_kernel(
    const int* __restrict__ boff, const unsigned* __restrict__ ebuf,
    const float* __restrict__ dinv, const __half* __restrict__ A1h,
    const float* __restrict__ b1, const float* __restrict__ W2,
    __half* __restrict__ A2h, int N) {
    __shared__ float acc[BKT][17];
    __shared__ float ldd[BKT];
    __shared__ float sW2[256];
    __shared__ float sb1[16];
    int b = blockIdx.x, t = threadIdx.x;
    int base = b * BKT;
    sW2[t] = W2[t];
    if (t < 16) sb1[t] = b1[t];
    if (t < BKT) {
        int n = base + t;
        ldd[t] = (n < N) ? dinv[n] : 0.f;
    }
    for (int k = t; k < BKT * 17; k += 256) ((float*)acc)[k] = 0.f;
    __syncthreads();

    int ebeg = boff[b * SUBC], eend = boff[b * SUBC + SUBC];
    const uint2* H2 = (const uint2*)A1h;
    int q = t & 3;
    int e = ebeg + (t >> 2);
    for (; e + 64 < eend; e += 128) {
        unsigned u0 = ebuf[e], u1 = ebuf[e + 64];
        edge_accum(u0, q, H2, acc);
        edge_accum(u1, q, H2, acc);
    }
    if (e < eend) edge_accum(ebuf[e], q, H2, acc);
    __syncthreads();

    // epilogue: row = relu(dinv*(acc+self) + b1)
    if (t < BKT * 4) {
        int n = t >> 2, qq = t & 3;
        int node = base + n;
        if (node < N) {
            float dd = ldd[n];
            uint2 v = H2[(size_t)node * 4 + qq];
            __half2 h0 = *(const __half2*)&v.x;
            __half2 h1 = *(const __half2*)&v.y;
            float2 f0 = __half22float2(h0), f1 = __half22float2(h1);
            acc[n][qq*4+0] = fmaxf((acc[n][qq*4+0] + f0.x) * dd + sb1[qq*4+0], 0.f);
            acc[n][qq*4+1] = fmaxf((acc[n][qq*4+1] + f0.y) * dd + sb1[qq*4+1], 0.f);
            acc[n][qq*4+2] = fmaxf((acc[n][qq*4+2] + f1.x) * dd + sb1[qq*4+2], 0.f);
            acc[n][qq*4+3] = fmaxf((acc[n][qq*4+3] + f1.y) * dd + sb1[qq*4+3], 0.f);
        }
    }
    __syncthreads();

    // A2h[node] = (row @ W2^T) * dinv[node]  (fp16)
    if (t < BKT * 4) {
        int n = t >> 2, qq = t & 3;
        int node = base + n;
        if (node < N) {
            float dd = ldd[n];
            float o[4];
#pragma unroll
            for (int jj = 0; jj < 4; jj++) {
                int j = qq * 4 + jj;
                float a = 0.f;
#pragma unroll
                for (int k = 0; k < 16; k++) a += acc[n][k] * sW2[j * 16 + k];
                o[jj] = a * dd;
            }
            uint2 ov;
            *(__half2*)&ov.x = __floats2half2_rn(o[0], o[1]);
            *(__half2*)&ov.y = __floats2half2_rn(o[2], o[3]);
            ((uint2*)A2h)[(size_t)node * 4 + qq] = ov;
        }
    }
}

// ---- layer-2: bucket accumulate; out = dinv*(sum+self); segmented mean-pool flush ----
__global__ void __launch_bounds__(256) agg2_kernel(
    const int* __restrict__ boff, const unsigned* __restrict__ ebuf,
    const float* __restrict__ dinv, const __half* __restrict__ A2h,
    const int* __restrict__ batch, float* __restrict__ pooled,
    float* __restrict__ cnt, int N) {
    __shared__ float acc[BKT][17];
    __shared__ float ldd[BKT];
    __shared__ int ldsg[BKT];
    int b = blockIdx.x, t = threadIdx.x;
    int base = b * BKT;
    if (t < BKT) {
        int n = base + t;
        ldd[t] = (n < N) ? dinv[n] : 0.f;
    }
    for (int k = t; k < BKT * 17; k += 256) ((float*)acc)[k] = 0.f;
    __syncthreads();

    int ebeg = boff[b * SUBC], eend = boff[b * SUBC + SUBC];
    const uint2* H2 = (const uint2*)A2h;
    int q = t & 3;
    int e = ebeg + (t >> 2);
    for (; e + 64 < eend; e += 128) {
        unsigned u0 = ebuf[e], u1 = ebuf[e + 64];
        edge_accum(u0, q, H2, acc);
        edge_accum(u1, q, H2, acc);
    }
    if (e < eend) edge_accum(ebuf[e], q, H2, acc);
    __syncthreads();

    if (t < BKT) {
        int n = base + t;
        ldsg[t] = (n < N) ? batch[n] : -1;
    }
    if (t < BKT * 4) {
        int n = t >> 2, qq = t & 3;
        int node = base + n;
        if (node < N) {
            float dd = ldd[n];
            uint2 v = H2[(size_t)node * 4 + qq];
            __half2 h0 = *(const __half2*)&v.x;
            __half2 h1 = *(const __half2*)&v.y;
            float2 f0 = __half22float2(h0), f1 = __half22float2(h1);
            acc[n][qq*4+0] = (acc[n][qq*4+0] + f0.x) * dd;
            acc[n][qq*4+1] = (acc[n][qq*4+1] + f0.y) * dd;
            acc[n][qq*4+2] = (acc[n][qq*4+2] + f1.x) * dd;
            acc[n][qq*4+3] = (acc[n][qq*4+3] + f1.y) * dd;
        }
    }
    __syncthreads();

    // segmented pool flush (batch sorted)
    int nmax = N - base; if (nmax > BKT) nmax = BKT;
    if (t < 16 && nmax > 0) {
        int c = t;
        int g = ldsg[0];
        float a = 0.f, k = 0.f;
        for (int n = 0; n < nmax; n++) {
            int gi = ldsg[n];
            if (gi != g) {
                atomicAdd(&pooled[(size_t)g * 16 + c], a);
                if (c == 0) atomicAdd(&cnt[g], k);
                a = 0.f; k = 0.f; g = gi;
            }
            a += acc[n][c];
            k += 1.f;
        }
        atomicAdd(&pooled[(size_t)g * 16 + c], a);
        if (c == 0) atomicAdd(&cnt[g], k);
    }
}

// ---- head: mean finish (+b2), logits = pooled @ Wl^T + bl, softmax ----
__global__ void head_kernel(const float* __restrict__ pooled, const float* __restrict__ cnt,
                            const float* __restrict__ b2, const float* __restrict__ Wl,
                            const float* __restrict__ bl, float* __restrict__ out) {
    int g = blockIdx.x * blockDim.x + threadIdx.x;
    if (g >= NG) return;
    float c = cnt[g];
    c = c > 1.0f ? c : 1.0f;
    float inv = 1.0f / c;
    float p[16];
#pragma unroll
    for (int j = 0; j < 16; j++) p[j] = pooled[(size_t)g * 16 + j] * inv + b2[j];
    float logits[5], m = -INFINITY;
#pragma unroll
    for (int r = 0; r < 5; r++) {
        float a = bl[r];
#pragma unroll
        for (int j = 0; j < 16; j++) a += p[j] * Wl[r * 16 + j];
        logits[r] = a;
        m = fmaxf(m, a);
    }
    float s = 0.f;
#pragma unroll
    for (int r = 0; r < 5; r++) { logits[r] = expf(logits[r] - m); s += logits[r]; }
    float is = 1.0f / s;
#pragma unroll
    for (int r = 0; r < 5; r++) out[(size_t)g * 5 + r] = logits[r] * is;
}

static inline size_t rnd16b(size_t bytes) { return (bytes + 15) & ~(size_t)15; }

extern "C" void kernel_launch(void* const* d_in, const int* in_sizes, int n_in,
                              void* d_out, int out_size, void* d_ws, size_t ws_size,
                              hipStream_t stream) {
    const float* x     = (const float*)d_in[0];
    const int*   edge  = (const int*)d_in[1];   // [2, E]: first E = src, next E = dst
    const int*   batch = (const int*)d_in[2];
    const float* W1    = (const float*)d_in[3];
    const float* b1    = (const float*)d_in[4];
    const float* W2    = (const float*)d_in[5];
    const float* b2    = (const float*)d_in[6];
    const float* Wl    = (const float*)d_in[7];
    const float* bl    = (const float*)d_in[8];

    const int N = in_sizes[0] / 32;
    const int E = in_sizes[1] / 2;
    const int* src = edge;
    const int* dst = edge + E;

    const int NB = (N + BKT - 1) / BKT;
    const int M  = NB * SUBC;

    // workspace layout; zeroed region first
    char* ws = (char*)d_ws;
    size_t off = 0;
    int*      bcnt   = (int*)(ws + off);      off += rnd16b((size_t)M * 4);
    float*    pooled = (float*)(ws + off);    off += rnd16b((size_t)NG * 16 * 4);
    float*    cnt    = (float*)(ws + off);    off += rnd16b((size_t)NG * 4);
    size_t zbytes = off;
    int*      degi   = (int*)(ws + off);      off += rnd16b((size_t)N * 4);
    float*    dinv   = (float*)(ws + off);    off += rnd16b((size_t)N * 4);
    int*      boff   = (int*)(ws + off);      off += rnd16b((size_t)(M + 1) * 4);
    int*      cur    = (int*)(ws + off);      off += rnd16b((size_t)M * 4);
    unsigned* ebuf   = (unsigned*)(ws + off); off += rnd16b((size_t)E * 4);
    __half*   A1h    = (__half*)(ws + off);   off += rnd16b((size_t)N * 16 * 2);
    __half*   A2h    = (__half*)(ws + off);   off += rnd16b((size_t)N * 16 * 2);

    hipMemsetAsync(d_ws, 0, zbytes, stream);

    const int BS = 256;
    int gE = (E + BS - 1) / BS;
    int gN = (N + BS - 1) / BS;

    count_kernel<<<gE, BS, 0, stream>>>(dst, bcnt, E);
    scan_kernel<<<1, 1024, 0, stream>>>(bcnt, boff, cur, M);
    scatter_kernel<<<gE, BS, 0, stream>>>(src, dst, cur, ebuf, E);
    hist_kernel<<<NB, 256, 0, stream>>>(boff, ebuf, degi, N);
    dinv_kernel<<<gN, BS, 0, stream>>>(degi, dinv, N);

    xform1_kernel<<<gN, BS, 0, stream>>>(x, W1, dinv, A1h, N);
    agg1_kernel<<<NB, 256, 0, stream>>>(boff, ebuf, dinv, A1h, b1, W2, A2h, N);
    agg2_kernel<<<NB, 256, 0, stream>>>(boff, ebuf, dinv, A2h, batch, pooled, cnt, N);
    head_kernel<<<(NG + BS - 1) / BS, BS, 0, stream>>>(pooled, cnt, b2, Wl, bl, (float*)d_out);
}

// Round 6
// 120.252 us; speedup vs baseline: 4.6221x; 4.1588x over previous
//
#include <hip/hip_runtime.h>
#include <hip/hip_fp16.h>
#include <math.h>

#define NG 1000
#define NPN 512        // nodes per partition
#define PSH 9          // log2(NPN)
#define MAXPART 256    // >= ceil(N/NPN); N=100K -> 196
#define K1BLK 256      // blocks for edge-chunk kernels

// ---- pass A1: per-chunk partition histogram -> global pcnt ----
__global__ void __launch_bounds__(256) pcount_kernel(const int* __restrict__ dst,
                                                     int* __restrict__ pcnt,
                                                     int E, int CH, int NPART) {
    __shared__ int h[MAXPART];
    int b = blockIdx.x, t = threadIdx.x;
    h[t] = 0;
    __syncthreads();
    int beg = b * CH, end = min(E, beg + CH);
    for (int e = beg + t; e < end; e += 256) atomicAdd(&h[dst[e] >> PSH], 1);
    __syncthreads();
    if (t < NPART && h[t] > 0) atomicAdd(&pcnt[t], h[t]);
}

// ---- pass A2: scan partition counts -> poff (exclusive), init pcur ----
__global__ void __launch_bounds__(256) pscan_kernel(const int* __restrict__ pcnt,
                                                    int* __restrict__ poff,
                                                    int* __restrict__ pcur,
                                                    int* __restrict__ rowptr,
                                                    int NPART, int N, int E) {
    __shared__ int sm[256];
    int t = threadIdx.x;
    int v = (t < NPART) ? pcnt[t] : 0;
    sm[t] = v;
    __syncthreads();
    for (int o = 1; o < 256; o <<= 1) {
        int u = (t >= o) ? sm[t - o] : 0;
        __syncthreads();
        sm[t] += u;
        __syncthreads();
    }
    int ex = sm[t] - v;
    if (t < NPART) { poff[t] = ex; pcur[t] = ex; }
    if (t == NPART - 1) poff[NPART] = ex + v;
    if (t == 0) rowptr[N] = E;
}

// ---- pass A3: scatter edges into partition-grouped ibuf (block-reserved runs) ----
__global__ void __launch_bounds__(256) pscatter_kernel(const int* __restrict__ src,
                                                       const int* __restrict__ dst,
                                                       int* __restrict__ pcur,
                                                       int* __restrict__ ibuf,
                                                       int E, int CH, int NPART) {
    __shared__ int h[MAXPART];
    __shared__ int gbase[MAXPART];
    int b = blockIdx.x, t = threadIdx.x;
    h[t] = 0;
    __syncthreads();
    int beg = b * CH, end = min(E, beg + CH);
    for (int e = beg + t; e < end; e += 256) atomicAdd(&h[dst[e] >> PSH], 1);
    __syncthreads();
    if (t < NPART) gbase[t] = (h[t] > 0) ? atomicAdd(&pcur[t], h[t]) : 0;
    __syncthreads();
    h[t] = 0;   // reuse as local cursor
    __syncthreads();
    for (int e = beg + t; e < end; e += 256) {
        int s = src[e], d = dst[e];
        int p = d >> PSH;
        int pos = gbase[p] + atomicAdd(&h[p], 1);
        ibuf[pos] = ((d & (NPN - 1)) << 17) | s;   // N < 2^17
    }
}

// ---- pass B: per-partition node-level CSR + rowptr + dinv (one block owns it) ----
__global__ void __launch_bounds__(256) part_kernel(const int* __restrict__ poff,
                                                   const int* __restrict__ ibuf,
                                                   int* __restrict__ csr,
                                                   int* __restrict__ rowptr,
                                                   float* __restrict__ dinv, int N) {
    __shared__ int h[NPN];
    __shared__ int ex[NPN];
    __shared__ int cur[NPN];
    __shared__ int sm[256];
    int p = blockIdx.x, t = threadIdx.x;
    int base = p * NPN;
    for (int k = t; k < NPN; k += 256) h[k] = 0;
    __syncthreads();
    int ebeg = poff[p], eend = poff[p + 1];
    for (int e = ebeg + t; e < eend; e += 256) atomicAdd(&h[ibuf[e] >> 17], 1);
    __syncthreads();
    // exclusive scan of 512 entries with 256 threads (2 per thread)
    int a0 = h[2 * t], a1 = h[2 * t + 1];
    int s = a0 + a1;
    sm[t] = s;
    __syncthreads();
    for (int o = 1; o < 256; o <<= 1) {
        int u = (t >= o) ? sm[t - o] : 0;
        __syncthreads();
        sm[t] += u;
        __syncthreads();
    }
    int exc = sm[t] - s;
    ex[2 * t] = exc;          cur[2 * t] = exc;
    ex[2 * t + 1] = exc + a0; cur[2 * t + 1] = exc + a0;
    __syncthreads();
    for (int k = t; k < NPN; k += 256) {
        int n = base + k;
        if (n < N) {
            rowptr[n] = ebeg + ex[k];
            dinv[n] = rsqrtf((float)h[k] + 1.0f);   // +1 self-loop
        }
    }
    for (int e = ebeg + t; e < eend; e += 256) {
        int w = ibuf[e];
        int ln = w >> 17;
        int pos = ebeg + atomicAdd(&cur[ln], 1);
        csr[pos] = w & 0x1FFFF;
    }
}

// ---- A1h[N,16] (fp16) = (X[N,32] @ W1^T) * dinv[i] ----
__global__ void xform1_kernel(const float* __restrict__ X, const float* __restrict__ W,
                              const float* __restrict__ dinv, __half* __restrict__ A1h, int N) {
    __shared__ float sW[16 * 32];
    for (int t = threadIdx.x; t < 512; t += blockDim.x) sW[t] = W[t];
    __syncthreads();
    int i = blockIdx.x * blockDim.x + threadIdx.x;
    if (i >= N) return;
    float xv[32];
    const float4* xp = (const float4*)(X + (size_t)i * 32);
#pragma unroll
    for (int q = 0; q < 8; q++) {
        float4 v = xp[q];
        xv[4*q+0] = v.x; xv[4*q+1] = v.y; xv[4*q+2] = v.z; xv[4*q+3] = v.w;
    }
    float dd = dinv[i];
    union { __half2 h2[8]; uint4 u4[2]; } pk;
#pragma unroll
    for (int j2 = 0; j2 < 8; j2++) {
        float o[2];
#pragma unroll
        for (int jj = 0; jj < 2; jj++) {
            int j = j2 * 2 + jj;
            float a = 0.f;
#pragma unroll
            for (int k = 0; k < 32; k++) a += xv[k] * sW[j * 32 + k];
            o[jj] = a * dd;
        }
        pk.h2[j2] = __floats2half2_rn(o[0], o[1]);
    }
    uint4* yp = (uint4*)(A1h + (size_t)i * 16);
    yp[0] = pk.u4[0];
    yp[1] = pk.u4[1];
}

__device__ __forceinline__ float4 h2f4(uint2 v) {
    float2 f0 = __half22float2(*(const __half2*)&v.x);
    float2 f1 = __half22float2(*(const __half2*)&v.y);
    return make_float4(f0.x, f0.y, f1.x, f1.y);
}

// ---- layer-1: gather-accumulate in regs; relu(dinv*(sum+self)+b1); @W2^T*dinv -> A2h ----
__global__ void __launch_bounds__(256) agg1_kernel(
    const int* __restrict__ rowptr, const int* __restrict__ csr,
    const float* __restrict__ dinv, const __half* __restrict__ A1h,
    const float* __restrict__ b1, const float* __restrict__ W2,
    __half* __restrict__ A2h, int N) {
    __shared__ float sW2[256];
    __shared__ float sb1[16];
    __shared__ float tile[64][17];
    int t = threadIdx.x;
    int team = t >> 2, q = t & 3;
    int node = blockIdx.x * 64 + team;
    sW2[t] = W2[t];
    if (t < 16) sb1[t] = b1[t];
    __syncthreads();
    const uint2* H2 = (const uint2*)A1h;
    float4 acc = make_float4(0.f, 0.f, 0.f, 0.f);
    float dd = 0.f;
    if (node < N) {
        dd = dinv[node];
        float4 sv = h2f4(H2[(size_t)node * 4 + q]);   // self (pre-scaled by dinv)
        acc = sv;
        int e = rowptr[node], end = rowptr[node + 1];
        for (; e + 1 < end; e += 2) {
            int s0 = csr[e], s1 = csr[e + 1];
            float4 g0 = h2f4(H2[(size_t)s0 * 4 + q]);
            float4 g1 = h2f4(H2[(size_t)s1 * 4 + q]);
            acc.x += g0.x + g1.x; acc.y += g0.y + g1.y;
            acc.z += g0.z + g1.z; acc.w += g0.w + g1.w;
        }
        if (e < end) {
            float4 g = h2f4(H2[(size_t)csr[e] * 4 + q]);
            acc.x += g.x; acc.y += g.y; acc.z += g.z; acc.w += g.w;
        }
        tile[team][q*4+0] = fmaxf(acc.x * dd + sb1[q*4+0], 0.f);
        tile[team][q*4+1] = fmaxf(acc.y * dd + sb1[q*4+1], 0.f);
        tile[team][q*4+2] = fmaxf(acc.z * dd + sb1[q*4+2], 0.f);
        tile[team][q*4+3] = fmaxf(acc.w * dd + sb1[q*4+3], 0.f);
    }
    __syncthreads();
    if (node < N) {
        float o[4];
#pragma unroll
        for (int jj = 0; jj < 4; jj++) {
            int j = q * 4 + jj;
            float a = 0.f;
#pragma unroll
            for (int k = 0; k < 16; k++) a += tile[team][k] * sW2[j * 16 + k];
            o[jj] = a * dd;
        }
        uint2 ov;
        *(__half2*)&ov.x = __floats2half2_rn(o[0], o[1]);
        *(__half2*)&ov.y = __floats2half2_rn(o[2], o[3]);
        ((uint2*)A2h)[(size_t)node * 4 + q] = ov;
    }
}

// ---- layer-2: gather-accumulate; dinv*(sum+self); segmented mean-pool flush ----
__global__ void __launch_bounds__(256) agg2_kernel(
    const int* __restrict__ rowptr, const int* __restrict__ csr,
    const float* __restrict__ dinv, const __half* __restrict__ A2h,
    const int* __restrict__ batch, float* __restrict__ pooled,
    float* __restrict__ cnt, int N) {
    __shared__ float tile[64][17];
    __shared__ int gb[64];
    int t = threadIdx.x;
    int team = t >> 2, q = t & 3;
    int base = blockIdx.x * 64;
    int node = base + team;
    if (t < 64) {
        int n = base + t;
        gb[t] = (n < N) ? batch[n] : -1;
    }
    const uint2* H2 = (const uint2*)A2h;
    if (node < N) {
        float dd = dinv[node];
        float4 acc = h2f4(H2[(size_t)node * 4 + q]);   // self
        int e = rowptr[node], end = rowptr[node + 1];
        for (; e + 1 < end; e += 2) {
            int s0 = csr[e], s1 = csr[e + 1];
            float4 g0 = h2f4(H2[(size_t)s0 * 4 + q]);
            float4 g1 = h2f4(H2[(size_t)s1 * 4 + q]);
            acc.x += g0.x + g1.x; acc.y += g0.y + g1.y;
            acc.z += g0.z + g1.z; acc.w += g0.w + g1.w;
        }
        if (e < end) {
            float4 g = h2f4(H2[(size_t)csr[e] * 4 + q]);
            acc.x += g.x; acc.y += g.y; acc.z += g.z; acc.w += g.w;
        }
        tile[team][q*4+0] = acc.x * dd;
        tile[team][q*4+1] = acc.y * dd;
        tile[team][q*4+2] = acc.z * dd;
        tile[team][q*4+3] = acc.w * dd;
    }
    __syncthreads();
    int nmax = N - base; if (nmax > 64) nmax = 64;
    if (t < 16 && nmax > 0) {
        int c = t;
        int g = gb[0];
        float a = 0.f, k = 0.f;
        for (int n = 0; n < nmax; n++) {
            int gi = gb[n];
            if (gi != g) {
                atomicAdd(&pooled[(size_t)g * 16 + c], a);
                if (c == 0) atomicAdd(&cnt[g], k);
                a = 0.f; k = 0.f; g = gi;
            }
            a += tile[n][c];
            k += 1.f;
        }
        atomicAdd(&pooled[(size_t)g * 16 + c], a);
        if (c == 0) atomicAdd(&cnt[g], k);
    }
}

// ---- head: mean finish (+b2), logits = pooled @ Wl^T + bl, softmax ----
__global__ void head_kernel(const float* __restrict__ pooled, const float* __restrict__ cnt,
                            const float* __restrict__ b2, const float* __restrict__ Wl,
                            const float* __restrict__ bl, float* __restrict__ out) {
    int g = blockIdx.x * blockDim.x + threadIdx.x;
    if (g >= NG) return;
    float c = cnt[g];
    c = c > 1.0f ? c : 1.0f;
    float inv = 1.0f / c;
    float p[16];
#pragma unroll
    for (int j = 0; j < 16; j++) p[j] = pooled[(size_t)g * 16 + j] * inv + b2[j];
    float logits[5], m = -INFINITY;
#pragma unroll
    for (int r = 0; r < 5; r++) {
        float a = bl[r];
#pragma unroll
        for (int j = 0; j < 16; j++) a += p[j] * Wl[r * 16 + j];
        logits[r] = a;
        m = fmaxf(m, a);
    }
    float s = 0.f;
#pragma unroll
    for (int r = 0; r < 5; r++) { logits[r] = expf(logits[r] - m); s += logits[r]; }
    float is = 1.0f / s;
#pragma unroll
    for (int r = 0; r < 5; r++) out[(size_t)g * 5 + r] = logits[r] * is;
}

static inline size_t rnd16b(size_t bytes) { return (bytes + 15) & ~(size_t)15; }

extern "C" void kernel_launch(void* const* d_in, const int* in_sizes, int n_in,
                              void* d_out, int out_size, void* d_ws, size_t ws_size,
                              hipStream_t stream) {
    const float* x     = (const float*)d_in[0];
    const int*   edge  = (const int*)d_in[1];   // [2, E]: first E = src, next E = dst
    const int*   batch = (const int*)d_in[2];
    const float* W1    = (const float*)d_in[3];
    const float* b1    = (const float*)d_in[4];
    const float* W2    = (const float*)d_in[5];
    const float* b2    = (const float*)d_in[6];
    const float* Wl    = (const float*)d_in[7];
    const float* bl    = (const float*)d_in[8];

    const int N = in_sizes[0] / 32;
    const int E = in_sizes[1] / 2;
    const int* src = edge;
    const int* dst = edge + E;

    const int NPART = (N + NPN - 1) / NPN;   // 196 for N=100K (<= MAXPART)
    const int CH = (E + K1BLK - 1) / K1BLK;

    // workspace layout; zeroed region first
    char* ws = (char*)d_ws;
    size_t off = 0;
    int*      pcnt   = (int*)(ws + off);      off += rnd16b((size_t)MAXPART * 4);
    float*    pooled = (float*)(ws + off);    off += rnd16b((size_t)NG * 16 * 4);
    float*    cnt    = (float*)(ws + off);    off += rnd16b((size_t)NG * 4);
    size_t zbytes = off;
    int*      poff   = (int*)(ws + off);      off += rnd16b((size_t)(MAXPART + 1) * 4);
    int*      pcur   = (int*)(ws + off);      off += rnd16b((size_t)MAXPART * 4);
    int*      rowptr = (int*)(ws + off);      off += rnd16b((size_t)(N + 1) * 4);
    float*    dinv   = (float*)(ws + off);    off += rnd16b((size_t)N * 4);
    int*      ibuf   = (int*)(ws + off);      off += rnd16b((size_t)E * 4);
    int*      csr    = (int*)(ws + off);      off += rnd16b((size_t)E * 4);
    __half*   A1h    = (__half*)(ws + off);   off += rnd16b((size_t)N * 16 * 2);
    __half*   A2h    = (__half*)(ws + off);   off += rnd16b((size_t)N * 16 * 2);

    hipMemsetAsync(d_ws, 0, zbytes, stream);

    const int BS = 256;
    int gN = (N + BS - 1) / BS;

    // CSR build (two-pass radix by dst)
    pcount_kernel<<<K1BLK, 256, 0, stream>>>(dst, pcnt, E, CH, NPART);
    pscan_kernel<<<1, 256, 0, stream>>>(pcnt, poff, pcur, rowptr, NPART, N, E);
    pscatter_kernel<<<K1BLK, 256, 0, stream>>>(src, dst, pcur, ibuf, E, CH, NPART);
    part_kernel<<<NPART, 256, 0, stream>>>(poff, ibuf, csr, rowptr, dinv, N);

    // dense transform + two fused conv layers + head
    xform1_kernel<<<gN, BS, 0, stream>>>(x, W1, dinv, A1h, N);
    int gAgg = (N + 63) / 64;
    agg1_kernel<<<gAgg, 256, 0, stream>>>(rowptr, csr, dinv, A1h, b1, W2, A2h, N);
    agg2_kernel<<<gAgg, 256, 0, stream>>>(rowptr, csr, dinv, A2h, batch, pooled, cnt, N);
    head_kernel<<<(NG + BS - 1) / BS, BS, 0, stream>>>(pooled, cnt, b2, Wl, bl, (float*)d_out);
}